// Round 6
// baseline (88.684 us; speedup 1.0000x reference)
//
#include <hip/hip_runtime.h>

typedef unsigned short u16;
typedef __attribute__((ext_vector_type(8))) __bf16 bf16x8;
typedef __attribute__((ext_vector_type(4))) float f32x4;
typedef __attribute__((ext_vector_type(8))) short short8;
typedef __attribute__((ext_vector_type(4))) u16 us4;

#define T_SEQ 1024
#define PW 1280   // P row: Q(512) K(512) QML(128) KML(128); V lives in Vtb

__device__ __forceinline__ u16 f2bf(float f) {
  unsigned u = __float_as_uint(f);
  u += 0x7fff + ((u >> 16) & 1);
  return (u16)(u >> 16);
}
__device__ __forceinline__ float bf2f(u16 v) {
  return __uint_as_float((unsigned)v << 16);
}

// exact per-qtile kv-tile occupancy masks (verified rounds 2-5)
__constant__ u16 GLOB_M[16] = {0x0101,0x0303,0x0707,0x0F0F,0x1F1F,0x3F3F,0x7F7F,0xFFFF,
                               0xFFFF,0x0307,0x070F,0x0F1F,0x1F3F,0x3F7F,0x7FFF,0xFFFF};
__constant__ u16 LOC_M[16]  = {0x0101,0x0303,0x0607,0x0C0D,0x1819,0x3031,0x6061,0xC0C1,
                               0x8183,0x0307,0x060F,0x0C1D,0x1839,0x3071,0x60E1,0xC1C1};

__device__ __forceinline__ void gll16(const u16* gp, u16* lp) {
  __builtin_amdgcn_global_load_lds((const __attribute__((address_space(1))) unsigned*)gp,
                                   (__attribute__((address_space(3))) unsigned*)lp, 16, 0, 0);
}

// Stage NISS*32 rows x 64 cols (bf16) into LDS: linear dest, inverse-swizzled src.
template<int NISS>
__device__ __forceinline__ void stage_sw(u16* lds, const u16* __restrict__ g,
                                         int ld, int tid) {
  const int w = tid >> 6;
#pragma unroll
  for (int i = 0; i < NISS; ++i) {
    int row = i * 32 + (tid >> 3);
    int cswz = ((tid & 7) << 4) ^ ((row & 7) << 4);
    gll16(g + (size_t)row * ld + (cswz >> 1), lds + i * 2048 + w * 512);
  }
}

// read a bf16x8 fragment at logical (row, colbyte) from a swizzled 64-col tile
__device__ __forceinline__ bf16x8 rd_sw(const u16* lds, int row, int colbyte) {
  return *(const bf16x8*)&lds[row * 64 + ((colbyte ^ ((row & 7) << 4)) >> 1)];
}

__global__ void prep_all(const float4* __restrict__ x, u16* __restrict__ xb,
                         const float* __restrict__ Wq, const float* __restrict__ Wk,
                         const float* __restrict__ Wv, const float* __restrict__ Wqml,
                         const float* __restrict__ Wkml, const float* __restrict__ Wp,
                         const float* __restrict__ bq, const float* __restrict__ bk,
                         const float* __restrict__ bv, const float* __restrict__ bqml,
                         const float* __restrict__ bkml,
                         u16* __restrict__ Wcat, u16* __restrict__ Wpx, float* __restrict__ bcat) {
  if (blockIdx.x < 2048) {
    int i = blockIdx.x * 256 + threadIdx.x;
    float4 v = x[i];
    us4 o = { f2bf(v.x), f2bf(v.y), f2bf(v.z), f2bf(v.w) };
    *(us4*)&xb[i * 4] = o;
    return;
  }
  int idx = (blockIdx.x - 2048) * 256 + threadIdx.x;
  const int NW = 1792 * 512;
  if (idx < NW) {
    int row = idx >> 9;
    float v;
    if (row < 512)       v = Wq[idx];
    else if (row < 1024) v = Wk[idx - 512 * 512];
    else if (row < 1536) v = Wv[idx - 1024 * 512];
    else if (row < 1664) v = Wqml[idx - 1536 * 512];
    else                 v = Wkml[idx - 1664 * 512];
    Wcat[idx] = f2bf(v);
    return;
  }
  int i2 = idx - NW;
  if (i2 < 512 * 640) {
    int n = i2 / 640, k2 = i2 - n * 640;
    float v = (k2 < 512) ? Wp[n * 512 + k2] : Wp[n * 512 + k2 - 384];
    Wpx[i2] = f2bf(v);
    return;
  }
  int i3 = i2 - 512 * 640;
  if (i3 < 1792) {
    float v;
    if (i3 < 512)       v = bq[i3];
    else if (i3 < 1024) v = bk[i3 - 512];
    else if (i3 < 1536) v = bv[i3 - 1024];
    else if (i3 < 1664) v = bqml[i3 - 1536];
    else                v = bkml[i3 - 1664];
    bcat[i3] = v;
  }
}

// ---------------- 128x128 QKV projection GEMM, BK=64, swizzled ----------------
__global__ __launch_bounds__(256) void gemm_qkv(
    const u16* __restrict__ A, const u16* __restrict__ Bw,
    const float* __restrict__ bias, u16* __restrict__ Pout, u16* __restrict__ Vtb) {
  __shared__ u16 As[2][8192];
  __shared__ u16 Bs[2][8192];
  const int tid = threadIdx.x;
  const int lane = tid & 63, w = tid >> 6;
  const int g = lane >> 4, c = lane & 15;
  const int n0 = blockIdx.x * 128, m0 = blockIdx.y * 128;
  const int wm = (w >> 1) * 64, wn = (w & 1) * 64;

  f32x4 acc[4][4] = {};
  stage_sw<4>(As[0], A + (size_t)m0 * 512, 512, tid);
  stage_sw<4>(Bs[0], Bw + (size_t)n0 * 512, 512, tid);
  __syncthreads();
  for (int ks = 0; ks < 8; ++ks) {
    int cur = ks & 1;
    if (ks + 1 < 8) {
      stage_sw<4>(As[cur ^ 1], A + (size_t)m0 * 512 + (ks + 1) * 64, 512, tid);
      stage_sw<4>(Bs[cur ^ 1], Bw + (size_t)n0 * 512 + (ks + 1) * 64, 512, tid);
    }
#pragma unroll
    for (int h = 0; h < 2; ++h) {
      bf16x8 av[4], bv[4];
#pragma unroll
      for (int f = 0; f < 4; ++f) {
        av[f] = rd_sw(As[cur], wm + f * 16 + c, h * 64 + g * 16);
        bv[f] = rd_sw(Bs[cur], wn + f * 16 + c, h * 64 + g * 16);
      }
#pragma unroll
      for (int fm = 0; fm < 4; ++fm)
#pragma unroll
        for (int fn = 0; fn < 4; ++fn)
          acc[fm][fn] = __builtin_amdgcn_mfma_f32_16x16x32_bf16(av[fm], bv[fn], acc[fm][fn], 0, 0, 0);
    }
    __syncthreads();
  }

  const bool isV = (n0 >= 1024 && n0 < 1536);
#pragma unroll
  for (int fm = 0; fm < 4; ++fm)
#pragma unroll
    for (int fn = 0; fn < 4; ++fn) {
      int row = m0 + wm + fm * 16 + g * 4;
      int col = n0 + wn + fn * 16 + c;
      float bb = bias[col];
      if (isV) {
        int d = col - 1024;
        int bidx = row >> 10, t = row & 1023;
        us4 pack = { f2bf(acc[fm][fn][0] + bb), f2bf(acc[fm][fn][1] + bb),
                     f2bf(acc[fm][fn][2] + bb), f2bf(acc[fm][fn][3] + bb) };
        *(us4*)&Vtb[((size_t)bidx * 512 + d) * 1024 + t] = pack;
      } else {
        int pcol = (col < 1024) ? col : col - 512;
#pragma unroll
        for (int r = 0; r < 4; ++r)
          Pout[(size_t)(row + r) * PW + pcol] = f2bf(acc[fm][fn][r] + bb);
      }
    }
}

// ---------------- output projection: 128x64 tiles, K=640, swizzled ----------------
__global__ __launch_bounds__(256) void gemm_out(
    const u16* __restrict__ A, const u16* __restrict__ Bw,
    const float* __restrict__ bias, float* __restrict__ Cout) {
  __shared__ u16 As[2][8192];
  __shared__ u16 Bs[2][4096];
  const int tid = threadIdx.x;
  const int lane = tid & 63, w = tid >> 6;
  const int g = lane >> 4, c = lane & 15;
  const int n0 = blockIdx.x * 64, m0 = blockIdx.y * 128;
  const int wm = (w >> 1) * 64, wn = (w & 1) * 32;

  f32x4 acc[4][2] = {};
  stage_sw<4>(As[0], A + (size_t)m0 * 640, 640, tid);
  stage_sw<2>(Bs[0], Bw + (size_t)n0 * 640, 640, tid);
  __syncthreads();
  for (int ks = 0; ks < 10; ++ks) {
    int cur = ks & 1;
    if (ks + 1 < 10) {
      stage_sw<4>(As[cur ^ 1], A + (size_t)m0 * 640 + (ks + 1) * 64, 640, tid);
      stage_sw<2>(Bs[cur ^ 1], Bw + (size_t)n0 * 640 + (ks + 1) * 64, 640, tid);
    }
#pragma unroll
    for (int h = 0; h < 2; ++h) {
      bf16x8 av[4], bv[2];
#pragma unroll
      for (int f = 0; f < 4; ++f)
        av[f] = rd_sw(As[cur], wm + f * 16 + c, h * 64 + g * 16);
#pragma unroll
      for (int f = 0; f < 2; ++f)
        bv[f] = rd_sw(Bs[cur], wn + f * 16 + c, h * 64 + g * 16);
#pragma unroll
      for (int fm = 0; fm < 4; ++fm)
#pragma unroll
        for (int fn = 0; fn < 2; ++fn)
          acc[fm][fn] = __builtin_amdgcn_mfma_f32_16x16x32_bf16(av[fm], bv[fn], acc[fm][fn], 0, 0, 0);
    }
    __syncthreads();
  }
#pragma unroll
  for (int fm = 0; fm < 4; ++fm)
#pragma unroll
    for (int fn = 0; fn < 2; ++fn)
#pragma unroll
      for (int r = 0; r < 4; ++r) {
        int row = m0 + wm + fm * 16 + g * 4 + r;
        int col = n0 + wn + fn * 16 + c;
        Cout[(size_t)row * 512 + col] = acc[fm][fn][r] + bias[col];
      }
}

// ---------------- attention (swapped-operand, per-lane softmax) ----------------
// grid (16 qt, 28 units, 4 b):
//  u 0..23 : causal heads 2..7, split 4-way over kv-tiles (kt%4) -> partials
//  u 24,25 : local heads 0,1 (direct)
//  u 26,27 : ml local passes (direct, weighted, Y cols 512..639)
__global__ __launch_bounds__(256) void attn_k(
    const u16* __restrict__ P, const u16* __restrict__ Vtb, u16* __restrict__ Y,
    u16* __restrict__ Part_o, float* __restrict__ Part_ml,
    const float* __restrict__ mix_w, const float* __restrict__ bias_clip,
    const float* __restrict__ bias_clip_ml) {
  __shared__ u16 Ks[4096];          // single 64x64 K tile (swizzled layout)
  __shared__ u16 Ps[4][16 * 72];    // per-wave P bounce: [q=c][k], stride 72
  const int tid = threadIdx.x, lane = tid & 63, w = tid >> 6;
  const int g = lane >> 4, c = lane & 15;
  const int qt = blockIdx.x, u = blockIdx.y, b = blockIdx.z;

  int qcol, kcol, vsel, outcol = 0, slot = -1;
  bool localMask = false;
  float kbias, wgt = 1.0f;
  unsigned mask;
  if (u < 24) {
    int h = 2 + (u >> 2), sp = u & 3; slot = u;
    qcol = h * 64; kcol = 512 + h * 64; vsel = h; kbias = bias_clip[h];
    mask = (unsigned)GLOB_M[qt] & (0x1111u << sp);
  } else if (u < 26) {
    int h = u - 24;
    qcol = h * 64; kcol = 512 + h * 64; vsel = h; outcol = h * 64;
    localMask = true; kbias = bias_clip[h];
    mask = LOC_M[qt];
  } else {
    int mh = u - 26;
    qcol = 1024 + mh * 64; kcol = 1152 + mh * 64; vsel = 2 + mh; outcol = 512 + mh * 64;
    localMask = true; kbias = bias_clip_ml[mh]; wgt = mix_w[mh * 2 + 1];
    mask = LOC_M[qt];
  }
  const size_t baseP = (size_t)b * T_SEQ * PW;
  const u16* __restrict__ Kbase = P + baseP + kcol;
  const u16* __restrict__ Vbase = Vtb + ((size_t)b * 512 + vsel * 64) * 1024;
  const int r0 = qt * 64 + w * 16;
  const int qg = r0 + c;                     // this lane's q row (global)

  // per-lane visibility bounds
  int tq = (qg < 2) ? 0 : ((qg < 513) ? 2 * qg - 3 : 2 * qg - 1024);
  int upmax = (tq - 1) >> 1;
  int lomax = (tq - 2) >> 1;
  int wmin = (localMask && qg >= 2) ? ((qg < 513 ? qg - 2 : qg - 513) - 3) : -1000000;

  float mM = -1e8f, lL = 0.0f;
  f32x4 o[4] = {};

  if (mask) {
    bf16x8 aq0 = *(const bf16x8*)&P[baseP + (size_t)qg * PW + qcol + g * 8];
    bf16x8 aq1 = *(const bf16x8*)&P[baseP + (size_t)qg * PW + qcol + 32 + g * 8];

    unsigned rem = mask;
    int kt = __ffs(rem) - 1; rem &= rem - 1;

    for (;;) {
      const int k0 = kt * 64;
      // V fragments straight from global (consumed after softmax -> hidden)
      bf16x8 vr[2][4];
#pragma unroll
      for (int ks2 = 0; ks2 < 2; ++ks2)
#pragma unroll
        for (int db = 0; db < 4; ++db)
          vr[ks2][db] = *(const bf16x8*)&Vbase[(size_t)(db * 16 + c) * 1024 + k0 + ks2 * 32 + g * 8];
      // stage K tile (direct to LDS)
      stage_sw<2>(Ks, Kbase + (size_t)k0 * PW, PW, tid);
      __syncthreads();           // implicit vmcnt(0): K staged (V also landed)

      // QK^T swapped: S^T[k][q] ; lane -> q = c, k = k0 + cb*16 + g*4 + r
      float s[4][4];
#pragma unroll
      for (int cb = 0; cb < 4; ++cb) {
        f32x4 accs = {};
        bf16x8 bk0 = rd_sw(Ks, cb * 16 + c, g * 16);
        bf16x8 bk1 = rd_sw(Ks, cb * 16 + c, 64 + g * 16);
        accs = __builtin_amdgcn_mfma_f32_16x16x32_bf16(bk0, aq0, accs, 0, 0, 0);
        accs = __builtin_amdgcn_mfma_f32_16x16x32_bf16(bk1, aq1, accs, 0, 0, 0);
#pragma unroll
        for (int r = 0; r < 4; ++r) s[cb][r] = accs[r] * 0.125f;
      }
      __syncthreads();           // all K reads done -> next stage is safe

      // mask + clip bias (per-lane scalar bounds)
#pragma unroll
      for (int cb = 0; cb < 4; ++cb) {
        int kb = k0 + cb * 16 + g * 4;
#pragma unroll
        for (int r = 0; r < 4; ++r) {
          int kk = kb + r;
          bool tok = kk < 2;
          bool low = kk >= 513;
          int jk = kk - (low ? 513 : 2);
          int bnd = low ? lomax : upmax;
          bool vis = tok | ((jk <= bnd) & (jk >= wmin));
          float addb = (kk == 1) ? kbias : 0.0f;
          s[cb][r] = vis ? (s[cb][r] + addb) : -1e9f;
        }
      }

      // per-lane online softmax: in-lane tree + 2 shfl rounds (4-lane group)
      float rmax = s[0][0];
#pragma unroll
      for (int cb = 0; cb < 4; ++cb)
#pragma unroll
        for (int r = 0; r < 4; ++r) rmax = fmaxf(rmax, s[cb][r]);
      rmax = fmaxf(rmax, __shfl_xor(rmax, 16));
      rmax = fmaxf(rmax, __shfl_xor(rmax, 32));
      float mnew = fmaxf(mM, rmax);
      float fr = __expf(mM - mnew);
      float psum = 0.0f;
#pragma unroll
      for (int cb = 0; cb < 4; ++cb)
#pragma unroll
        for (int r = 0; r < 4; ++r) {
          float p = __expf(s[cb][r] - mnew);
          s[cb][r] = p;
          psum += p;
        }
      psum += __shfl_xor(psum, 16);
      psum += __shfl_xor(psum, 32);
      lL = lL * fr + psum;
      mM = mnew;
#pragma unroll
      for (int db = 0; db < 4; ++db) o[db] *= fr;

      // P bounce: pack 4 k-consecutive values per write (per-wave region)
#pragma unroll
      for (int cb = 0; cb < 4; ++cb) {
        us4 pk = { f2bf(s[cb][0]), f2bf(s[cb][1]), f2bf(s[cb][2]), f2bf(s[cb][3]) };
        *(us4*)&Ps[w][c * 72 + cb * 16 + g * 4] = pk;
      }
      asm volatile("s_waitcnt lgkmcnt(0)" ::: "memory");
      __builtin_amdgcn_sched_barrier(0);

      // PV swapped: O^T[d][q] += V^T-frag x P-frag
#pragma unroll
      for (int ks2 = 0; ks2 < 2; ++ks2) {
        bf16x8 ap = *(const bf16x8*)&Ps[w][c * 72 + ks2 * 32 + g * 8];
#pragma unroll
        for (int db = 0; db < 4; ++db)
          o[db] = __builtin_amdgcn_mfma_f32_16x16x32_bf16(vr[ks2][db], ap, o[db], 0, 0, 0);
      }

      if (!rem) break;
      kt = __ffs(rem) - 1; rem &= rem - 1;
    }
  }

  // epilogue: lane holds q = qg; o[db][r] = O[q][d = db*16 + g*4 + r]
  if (slot >= 0) {
    u16* po = Part_o + ((size_t)(slot * 4 + b)) * T_SEQ * 64;
#pragma unroll
    for (int db = 0; db < 4; ++db) {
      us4 pk = { f2bf(o[db][0]), f2bf(o[db][1]), f2bf(o[db][2]), f2bf(o[db][3]) };
      *(us4*)&po[(size_t)qg * 64 + db * 16 + g * 4] = pk;
    }
    if (g == 0) {
      float2 ml = { mM, lL };
      *(float2*)&Part_ml[(((size_t)(slot * 4 + b)) * T_SEQ + qg) * 2] = ml;
    }
  } else {
    float wl = wgt / lL;
#pragma unroll
    for (int db = 0; db < 4; ++db) {
      us4 pk = { f2bf(o[db][0] * wl), f2bf(o[db][1] * wl),
                 f2bf(o[db][2] * wl), f2bf(o[db][3] * wl) };
      *(us4*)&Y[((size_t)b * T_SEQ + qg) * 640 + outcol + db * 16 + g * 4] = pk;
    }
  }
}

// combine 4-way split partials for heads 2..7 -> Y cols 128..511
__global__ __launch_bounds__(256) void combine_k(
    const u16* __restrict__ Part_o, const float* __restrict__ Part_ml,
    u16* __restrict__ Y, const float* __restrict__ mix_w) {
  int idx = blockIdx.x * 256 + threadIdx.x;  // 6 heads * 4 b * 1024 rows * 16 quads
  int q4 = idx & 15;
  int row = (idx >> 4) & 1023;
  int bb = (idx >> 14) & 3;
  int hp = idx >> 16;
  float mv[4], lv[4];
  float ms = -1e30f;
#pragma unroll
  for (int s = 0; s < 4; ++s) {
    size_t base = (((size_t)(hp * 4 + s) * 4 + bb) * 1024 + row) * 2;
    mv[s] = Part_ml[base];
    lv[s] = Part_ml[base + 1];
    ms = fmaxf(ms, mv[s]);
  }
  float denom = 0.0f, e[4];
#pragma unroll
  for (int s = 0; s < 4; ++s) { e[s] = __expf(mv[s] - ms); denom += lv[s] * e[s]; }
  float wgt = (hp < 2) ? mix_w[hp * 2] : 1.0f;
  float inv = wgt / denom;
  float out[4] = {0.f, 0.f, 0.f, 0.f};
#pragma unroll
  for (int s = 0; s < 4; ++s) {
    us4 ov = *(const us4*)&Part_o[(((size_t)(hp * 4 + s) * 4 + bb) * 1024 + row) * 64 + q4 * 4];
#pragma unroll
    for (int j = 0; j < 4; ++j) out[j] += e[s] * bf2f(ov[j]);
  }
  us4 pk = { f2bf(out[0] * inv), f2bf(out[1] * inv), f2bf(out[2] * inv), f2bf(out[3] * inv) };
  *(us4*)&Y[((size_t)bb * 1024 + row) * 640 + (hp + 2) * 64 + q4 * 4] = pk;
}

extern "C" void kernel_launch(void* const* d_in, const int* in_sizes, int n_in,
                              void* d_out, int out_size, void* d_ws, size_t ws_size,
                              hipStream_t stream) {
  const float* x     = (const float*)d_in[0];
  const float* Wq    = (const float*)d_in[2];
  const float* bq    = (const float*)d_in[3];
  const float* Wk    = (const float*)d_in[4];
  const float* bk    = (const float*)d_in[5];
  const float* Wv    = (const float*)d_in[6];
  const float* bv    = (const float*)d_in[7];
  const float* Wqml  = (const float*)d_in[8];
  const float* bqml  = (const float*)d_in[9];
  const float* Wkml  = (const float*)d_in[10];
  const float* bkml  = (const float*)d_in[11];
  const float* mixw  = (const float*)d_in[12];
  const float* Wp    = (const float*)d_in[13];
  const float* bp    = (const float*)d_in[14];
  const float* bclip = (const float*)d_in[15];
  const float* bclipml = (const float*)d_in[16];

  u16* xb   = (u16*)d_ws;                  // 4096*512
  u16* Wcat = xb + 4096 * 512;             // 1792*512
  u16* Wpx  = Wcat + 1792 * 512;           // 512*640
  u16* Ybuf = Wpx + 512 * 640;             // 4096*640
  u16* Vtb  = Ybuf + 4096 * 640;           // 4*512*1024
  u16* Pbuf = Vtb + 4 * 512 * 1024;        // 4096*1280
  float* bcat = (float*)(Pbuf + 4096 * 1280);  // 2048 f32
  u16* Part_o = (u16*)(bcat + 2048);       // 24*4*1024*64 bf16 = 12.6 MB
  float* Part_ml = (float*)(Part_o + 24 * 4 * 1024 * 64);  // 24*4*1024*2 f32

  prep_all<<<6919, 256, 0, stream>>>((const float4*)x, xb, Wq, Wk, Wv, Wqml, Wkml, Wp,
                                     bq, bk, bv, bqml, bkml, Wcat, Wpx, bcat);
  gemm_qkv<<<dim3(14, 32), 256, 0, stream>>>(xb, Wcat, bcat, Pbuf, Vtb);
  attn_k<<<dim3(16, 28, 4), 256, 0, stream>>>(Pbuf, Vtb, Ybuf, Part_o, Part_ml,
                                              mixw, bclip, bclipml);
  combine_k<<<1536, 256, 0, stream>>>(Part_o, Part_ml, Ybuf, mixw);
  gemm_out<<<dim3(8, 32), 256, 0, stream>>>(Ybuf, Wpx, bp, (float*)d_out);
}

// Round 7
// 80.653 us; speedup vs baseline: 1.0996x; 1.0996x over previous
//
#include <hip/hip_runtime.h>

typedef unsigned short u16;
typedef __attribute__((ext_vector_type(8))) __bf16 bf16x8;
typedef __attribute__((ext_vector_type(4))) float f32x4;
typedef __attribute__((ext_vector_type(8))) short short8;
typedef __attribute__((ext_vector_type(4))) u16 us4;

#define T_SEQ 1024
#define PW 1280   // P row: Q(512) K(512) QML(128) KML(128); V lives in Vtb

__device__ __forceinline__ u16 f2bf(float f) {
  unsigned u = __float_as_uint(f);
  u += 0x7fff + ((u >> 16) & 1);
  return (u16)(u >> 16);
}
__device__ __forceinline__ float bf2f(u16 v) {
  return __uint_as_float((unsigned)v << 16);
}

// exact per-qtile kv-tile occupancy masks (verified rounds 2-6)
__constant__ u16 GLOB_M[16] = {0x0101,0x0303,0x0707,0x0F0F,0x1F1F,0x3F3F,0x7F7F,0xFFFF,
                               0xFFFF,0x0307,0x070F,0x0F1F,0x1F3F,0x3F7F,0x7FFF,0xFFFF};
__constant__ u16 LOC_M[16]  = {0x0101,0x0303,0x0607,0x0C0D,0x1819,0x3031,0x6061,0xC0C1,
                               0x8183,0x0307,0x060F,0x0C1D,0x1839,0x3071,0x60E1,0xC1C1};

__device__ __forceinline__ void gll16(const u16* gp, u16* lp) {
  __builtin_amdgcn_global_load_lds((const __attribute__((address_space(1))) unsigned*)gp,
                                   (__attribute__((address_space(3))) unsigned*)lp, 16, 0, 0);
}

// 256-thread stage: NISS*32 rows x 64 cols, linear LDS dest, inv-swizzled src
template<int NISS>
__device__ __forceinline__ void stage_sw(u16* lds, const u16* __restrict__ g,
                                         int ld, int tid) {
  const int w = tid >> 6;
#pragma unroll
  for (int i = 0; i < NISS; ++i) {
    int row = i * 32 + (tid >> 3);
    int cswz = ((tid & 7) << 4) ^ ((row & 7) << 4);
    gll16(g + (size_t)row * ld + (cswz >> 1), lds + i * 2048 + w * 512);
  }
}

// 512-thread stage: full 64x64 bf16 tile in ONE gll instr per thread
__device__ __forceinline__ void stage8(u16* lds, const u16* __restrict__ g,
                                       int ld, int tid) {
  int row = tid >> 3;
  int cswz = (((tid & 7) << 4) ^ ((row & 7) << 4)) >> 1;   // u16 units
  gll16(g + (size_t)row * ld + cswz, lds + (tid >> 6) * 512);
}

// read bf16x8 fragment at logical (row, colbyte) from a swizzled 64-col tile
__device__ __forceinline__ bf16x8 rd_sw(const u16* lds, int row, int colbyte) {
  return *(const bf16x8*)&lds[row * 64 + ((colbyte ^ ((row & 7) << 4)) >> 1)];
}

__global__ void prep_all(const float4* __restrict__ x, u16* __restrict__ xb,
                         const float* __restrict__ Wq, const float* __restrict__ Wk,
                         const float* __restrict__ Wv, const float* __restrict__ Wqml,
                         const float* __restrict__ Wkml, const float* __restrict__ Wp,
                         const float* __restrict__ bq, const float* __restrict__ bk,
                         const float* __restrict__ bv, const float* __restrict__ bqml,
                         const float* __restrict__ bkml,
                         u16* __restrict__ Wcat, u16* __restrict__ Wpx, float* __restrict__ bcat) {
  if (blockIdx.x < 2048) {
    int i = blockIdx.x * 256 + threadIdx.x;
    float4 v = x[i];
    us4 o = { f2bf(v.x), f2bf(v.y), f2bf(v.z), f2bf(v.w) };
    *(us4*)&xb[i * 4] = o;
    return;
  }
  int idx = (blockIdx.x - 2048) * 256 + threadIdx.x;
  const int NW = 1792 * 512;
  if (idx < NW) {
    int row = idx >> 9;
    float v;
    if (row < 512)       v = Wq[idx];
    else if (row < 1024) v = Wk[idx - 512 * 512];
    else if (row < 1536) v = Wv[idx - 1024 * 512];
    else if (row < 1664) v = Wqml[idx - 1536 * 512];
    else                 v = Wkml[idx - 1664 * 512];
    Wcat[idx] = f2bf(v);
    return;
  }
  int i2 = idx - NW;
  if (i2 < 512 * 640) {
    int n = i2 / 640, k2 = i2 - n * 640;
    float v = (k2 < 512) ? Wp[n * 512 + k2] : Wp[n * 512 + k2 - 384];
    Wpx[i2] = f2bf(v);
    return;
  }
  int i3 = i2 - 512 * 640;
  if (i3 < 1792) {
    float v;
    if (i3 < 512)       v = bq[i3];
    else if (i3 < 1024) v = bk[i3 - 512];
    else if (i3 < 1536) v = bv[i3 - 1024];
    else if (i3 < 1664) v = bqml[i3 - 1536];
    else                v = bkml[i3 - 1664];
    bcat[i3] = v;
  }
}

// ---------------- 128x128 QKV projection GEMM, BK=64, swizzled ----------------
__global__ __launch_bounds__(256) void gemm_qkv(
    const u16* __restrict__ A, const u16* __restrict__ Bw,
    const float* __restrict__ bias, u16* __restrict__ Pout, u16* __restrict__ Vtb) {
  __shared__ u16 As[2][8192];
  __shared__ u16 Bs[2][8192];
  const int tid = threadIdx.x;
  const int lane = tid & 63, w = tid >> 6;
  const int g = lane >> 4, c = lane & 15;
  const int n0 = blockIdx.x * 128, m0 = blockIdx.y * 128;
  const int wm = (w >> 1) * 64, wn = (w & 1) * 64;

  f32x4 acc[4][4] = {};
  stage_sw<4>(As[0], A + (size_t)m0 * 512, 512, tid);
  stage_sw<4>(Bs[0], Bw + (size_t)n0 * 512, 512, tid);
  __syncthreads();
  for (int ks = 0; ks < 8; ++ks) {
    int cur = ks & 1;
    if (ks + 1 < 8) {
      stage_sw<4>(As[cur ^ 1], A + (size_t)m0 * 512 + (ks + 1) * 64, 512, tid);
      stage_sw<4>(Bs[cur ^ 1], Bw + (size_t)n0 * 512 + (ks + 1) * 64, 512, tid);
    }
#pragma unroll
    for (int h = 0; h < 2; ++h) {
      bf16x8 av[4], bv[4];
#pragma unroll
      for (int f = 0; f < 4; ++f) {
        av[f] = rd_sw(As[cur], wm + f * 16 + c, h * 64 + g * 16);
        bv[f] = rd_sw(Bs[cur], wn + f * 16 + c, h * 64 + g * 16);
      }
#pragma unroll
      for (int fm = 0; fm < 4; ++fm)
#pragma unroll
        for (int fn = 0; fn < 4; ++fn)
          acc[fm][fn] = __builtin_amdgcn_mfma_f32_16x16x32_bf16(av[fm], bv[fn], acc[fm][fn], 0, 0, 0);
    }
    __syncthreads();
  }

  const bool isV = (n0 >= 1024 && n0 < 1536);
#pragma unroll
  for (int fm = 0; fm < 4; ++fm)
#pragma unroll
    for (int fn = 0; fn < 4; ++fn) {
      int row = m0 + wm + fm * 16 + g * 4;
      int col = n0 + wn + fn * 16 + c;
      float bb = bias[col];
      if (isV) {
        int d = col - 1024;
        int bidx = row >> 10, t = row & 1023;
        us4 pack = { f2bf(acc[fm][fn][0] + bb), f2bf(acc[fm][fn][1] + bb),
                     f2bf(acc[fm][fn][2] + bb), f2bf(acc[fm][fn][3] + bb) };
        *(us4*)&Vtb[((size_t)bidx * 512 + d) * 1024 + t] = pack;
      } else {
        int pcol = (col < 1024) ? col : col - 512;
#pragma unroll
        for (int r = 0; r < 4; ++r)
          Pout[(size_t)(row + r) * PW + pcol] = f2bf(acc[fm][fn][r] + bb);
      }
    }
}

// ---------------- output projection: 128x64 tiles, K=640, swizzled ----------------
__global__ __launch_bounds__(256) void gemm_out(
    const u16* __restrict__ A, const u16* __restrict__ Bw,
    const float* __restrict__ bias, float* __restrict__ Cout) {
  __shared__ u16 As[2][8192];
  __shared__ u16 Bs[2][4096];
  const int tid = threadIdx.x;
  const int lane = tid & 63, w = tid >> 6;
  const int g = lane >> 4, c = lane & 15;
  const int n0 = blockIdx.x * 64, m0 = blockIdx.y * 128;
  const int wm = (w >> 1) * 64, wn = (w & 1) * 32;

  f32x4 acc[4][2] = {};
  stage_sw<4>(As[0], A + (size_t)m0 * 640, 640, tid);
  stage_sw<2>(Bs[0], Bw + (size_t)n0 * 640, 640, tid);
  __syncthreads();
  for (int ks = 0; ks < 10; ++ks) {
    int cur = ks & 1;
    if (ks + 1 < 10) {
      stage_sw<4>(As[cur ^ 1], A + (size_t)m0 * 640 + (ks + 1) * 64, 640, tid);
      stage_sw<2>(Bs[cur ^ 1], Bw + (size_t)n0 * 640 + (ks + 1) * 64, 640, tid);
    }
#pragma unroll
    for (int h = 0; h < 2; ++h) {
      bf16x8 av[4], bv[2];
#pragma unroll
      for (int f = 0; f < 4; ++f)
        av[f] = rd_sw(As[cur], wm + f * 16 + c, h * 64 + g * 16);
#pragma unroll
      for (int f = 0; f < 2; ++f)
        bv[f] = rd_sw(Bs[cur], wn + f * 16 + c, h * 64 + g * 16);
#pragma unroll
      for (int fm = 0; fm < 4; ++fm)
#pragma unroll
        for (int fn = 0; fn < 2; ++fn)
          acc[fm][fn] = __builtin_amdgcn_mfma_f32_16x16x32_bf16(av[fm], bv[fn], acc[fm][fn], 0, 0, 0);
    }
    __syncthreads();
  }
#pragma unroll
  for (int fm = 0; fm < 4; ++fm)
#pragma unroll
    for (int fn = 0; fn < 2; ++fn)
#pragma unroll
      for (int r = 0; r < 4; ++r) {
        int row = m0 + wm + fm * 16 + g * 4 + r;
        int col = n0 + wn + fn * 16 + c;
        Cout[(size_t)row * 512 + col] = acc[fm][fn][r] + bias[col];
      }
}

// ---------------- attention: 8-wave blocks, counted-vmcnt pipeline ----------------
// grid (8 qt2, 28 units, 4 b); each block owns 128 q-rows (wave w -> 16 rows).
//  u 0..23 : causal heads 2..7, split 4-way over kv-tiles (kt%4) -> partials
//  u 24,25 : local heads 0,1 (direct)
//  u 26,27 : ml local passes (direct, weighted, Y cols 512..639)
__global__ __launch_bounds__(512, 6) void attn_k(
    const u16* __restrict__ P, const u16* __restrict__ Vtb, u16* __restrict__ Y,
    u16* __restrict__ Part_o, float* __restrict__ Part_ml,
    const float* __restrict__ mix_w, const float* __restrict__ bias_clip,
    const float* __restrict__ bias_clip_ml) {
  __shared__ u16 Ks[2][4096];   // K tile  [k][d]  (swizzled), 8 KB/slot
  __shared__ u16 Vs[2][4096];   // V^T tile [d][k] (swizzled), 8 KB/slot
  __shared__ u16 Ps[8][1152];   // per-wave P bounce [q=c][k], stride 72
  const int tid = threadIdx.x, lane = tid & 63, w = tid >> 6;
  const int g = lane >> 4, c = lane & 15;
  const int qt2 = blockIdx.x, u = blockIdx.y, b = blockIdx.z;

  int qcol, kcol, vsel, outcol = 0, slot = -1;
  bool localMask = false;
  float kbias, wgt = 1.0f;
  unsigned mask;
  if (u < 24) {
    int h = 2 + (u >> 2), sp = u & 3; slot = u;
    qcol = h * 64; kcol = 512 + h * 64; vsel = h; kbias = bias_clip[h];
    mask = ((unsigned)GLOB_M[2 * qt2] | (unsigned)GLOB_M[2 * qt2 + 1]) & (0x1111u << sp);
  } else if (u < 26) {
    int h = u - 24;
    qcol = h * 64; kcol = 512 + h * 64; vsel = h; outcol = h * 64;
    localMask = true; kbias = bias_clip[h];
    mask = (unsigned)LOC_M[2 * qt2] | (unsigned)LOC_M[2 * qt2 + 1];
  } else {
    int mh = u - 26;
    qcol = 1024 + mh * 64; kcol = 1152 + mh * 64; vsel = 2 + mh; outcol = 512 + mh * 64;
    localMask = true; kbias = bias_clip_ml[mh]; wgt = mix_w[mh * 2 + 1];
    mask = (unsigned)LOC_M[2 * qt2] | (unsigned)LOC_M[2 * qt2 + 1];
  }
  const size_t baseP = (size_t)b * T_SEQ * PW;
  const u16* __restrict__ Kbase = P + baseP + kcol;
  const u16* __restrict__ Vbase = Vtb + ((size_t)b * 512 + vsel * 64) * 1024;
  const int r0 = qt2 * 128 + w * 16;
  const int qg = r0 + c;                     // this lane's q row (global)

  // per-lane visibility bounds (verified R6)
  int tq = (qg < 2) ? 0 : ((qg < 513) ? 2 * qg - 3 : 2 * qg - 1024);
  int upmax = (tq - 1) >> 1;
  int lomax = (tq - 2) >> 1;
  int wmin = (localMask && qg >= 2) ? ((qg < 513 ? qg - 2 : qg - 513) - 3) : -1000000;

  float mM = -1e8f, lL = 0.0f;
  f32x4 o[4] = {};

  if (mask) {
    bf16x8 aq0 = *(const bf16x8*)&P[baseP + (size_t)qg * PW + qcol + g * 8];
    bf16x8 aq1 = *(const bf16x8*)&P[baseP + (size_t)qg * PW + qcol + 32 + g * 8];

    unsigned rem = mask;
    int kt_cur = __ffs(rem) - 1; rem &= rem - 1;
    stage8(Ks[0], Kbase + (size_t)(kt_cur * 64) * PW, PW, tid);
    stage8(Vs[0], Vbase + kt_cur * 64, 1024, tid);
    int kt_nxt = -1;
    if (rem) {
      kt_nxt = __ffs(rem) - 1; rem &= rem - 1;
      stage8(Ks[1], Kbase + (size_t)(kt_nxt * 64) * PW, PW, tid);
      stage8(Vs[1], Vbase + kt_nxt * 64, 1024, tid);
    }
    int cur = 0;

    for (;;) {
      // wait own loads for current tile; keep next tile's 2 loads in flight
      if (kt_nxt >= 0) asm volatile("s_waitcnt vmcnt(2)" ::: "memory");
      else             asm volatile("s_waitcnt vmcnt(0)" ::: "memory");
      __builtin_amdgcn_sched_barrier(0);
      __builtin_amdgcn_s_barrier();          // all waves: slot `cur` is full

      const int k0 = kt_cur * 64;

      // QK^T swapped: S^T[k][q]; lane -> q = c, k = k0 + cb*16 + g*4 + r
      float s[4][4];
#pragma unroll
      for (int cb = 0; cb < 4; ++cb) {
        f32x4 accs = {};
        bf16x8 bk0 = rd_sw(Ks[cur], cb * 16 + c, g * 16);
        bf16x8 bk1 = rd_sw(Ks[cur], cb * 16 + c, 64 + g * 16);
        accs = __builtin_amdgcn_mfma_f32_16x16x32_bf16(bk0, aq0, accs, 0, 0, 0);
        accs = __builtin_amdgcn_mfma_f32_16x16x32_bf16(bk1, aq1, accs, 0, 0, 0);
#pragma unroll
        for (int r = 0; r < 4; ++r) s[cb][r] = accs[r] * 0.125f;
      }

      // mask + clip bias (per-lane scalar bounds)
#pragma unroll
      for (int cb = 0; cb < 4; ++cb) {
        int kb = k0 + cb * 16 + g * 4;
#pragma unroll
        for (int r = 0; r < 4; ++r) {
          int kk = kb + r;
          bool tok = kk < 2;
          bool low = kk >= 513;
          int jk = kk - (low ? 513 : 2);
          int bnd = low ? lomax : upmax;
          bool vis = tok | ((jk <= bnd) & (jk >= wmin));
          float addb = (kk == 1) ? kbias : 0.0f;
          s[cb][r] = vis ? (s[cb][r] + addb) : -1e9f;
        }
      }

      // per-lane online softmax: in-lane tree + 2 shfl rounds
      float rmax = s[0][0];
#pragma unroll
      for (int cb = 0; cb < 4; ++cb)
#pragma unroll
        for (int r = 0; r < 4; ++r) rmax = fmaxf(rmax, s[cb][r]);
      rmax = fmaxf(rmax, __shfl_xor(rmax, 16));
      rmax = fmaxf(rmax, __shfl_xor(rmax, 32));
      float mnew = fmaxf(mM, rmax);
      float fr = __expf(mM - mnew);
      float psum = 0.0f;
#pragma unroll
      for (int cb = 0; cb < 4; ++cb)
#pragma unroll
        for (int r = 0; r < 4; ++r) {
          float p = __expf(s[cb][r] - mnew);
          s[cb][r] = p;
          psum += p;
        }
      psum += __shfl_xor(psum, 16);
      psum += __shfl_xor(psum, 32);
      lL = lL * fr + psum;
      mM = mnew;
#pragma unroll
      for (int db = 0; db < 4; ++db) o[db] *= fr;

      // P bounce (per-wave LDS region, no cross-wave sync)
#pragma unroll
      for (int cb = 0; cb < 4; ++cb) {
        us4 pk = { f2bf(s[cb][0]), f2bf(s[cb][1]), f2bf(s[cb][2]), f2bf(s[cb][3]) };
        *(us4*)&Ps[w][c * 72 + cb * 16 + g * 4] = pk;
      }
      asm volatile("s_waitcnt lgkmcnt(0)" ::: "memory");
      __builtin_amdgcn_sched_barrier(0);

      // PV swapped: O^T[d][q] += V^T-frag x P-frag (V from LDS, coalesced-staged)
#pragma unroll
      for (int ks2 = 0; ks2 < 2; ++ks2) {
        bf16x8 ap = *(const bf16x8*)&Ps[w][c * 72 + ks2 * 32 + g * 8];
#pragma unroll
        for (int db = 0; db < 4; ++db) {
          bf16x8 av = rd_sw(Vs[cur], db * 16 + c, ks2 * 64 + g * 16);
          o[db] = __builtin_amdgcn_mfma_f32_16x16x32_bf16(av, ap, o[db], 0, 0, 0);
        }
      }

      __builtin_amdgcn_s_barrier();          // all waves done reading slot `cur`
      if (kt_nxt < 0) break;
      int kt_nn = -1;
      if (rem) {
        kt_nn = __ffs(rem) - 1; rem &= rem - 1;
        stage8(Ks[cur], Kbase + (size_t)(kt_nn * 64) * PW, PW, tid);
        stage8(Vs[cur], Vbase + kt_nn * 64, 1024, tid);
      }
      kt_cur = kt_nxt; kt_nxt = kt_nn; cur ^= 1;
    }
  }

  // epilogue: lane holds q = qg; o[db][r] = O[q][d = db*16 + g*4 + r]
  if (slot >= 0) {
    u16* po = Part_o + ((size_t)(slot * 4 + b)) * T_SEQ * 64;
#pragma unroll
    for (int db = 0; db < 4; ++db) {
      us4 pk = { f2bf(o[db][0]), f2bf(o[db][1]), f2bf(o[db][2]), f2bf(o[db][3]) };
      *(us4*)&po[(size_t)qg * 64 + db * 16 + g * 4] = pk;
    }
    if (g == 0) {
      float2 ml = { mM, lL };
      *(float2*)&Part_ml[(((size_t)(slot * 4 + b)) * T_SEQ + qg) * 2] = ml;
    }
  } else {
    float wl = wgt / lL;
#pragma unroll
    for (int db = 0; db < 4; ++db) {
      us4 pk = { f2bf(o[db][0] * wl), f2bf(o[db][1] * wl),
                 f2bf(o[db][2] * wl), f2bf(o[db][3] * wl) };
      *(us4*)&Y[((size_t)b * T_SEQ + qg) * 640 + outcol + db * 16 + g * 4] = pk;
    }
  }
}

// combine 4-way split partials for heads 2..7 -> Y cols 128..511
__global__ __launch_bounds__(256) void combine_k(
    const u16* __restrict__ Part_o, const float* __restrict__ Part_ml,
    u16* __restrict__ Y, const float* __restrict__ mix_w) {
  int idx = blockIdx.x * 256 + threadIdx.x;  // 6 heads * 4 b * 1024 rows * 16 quads
  int q4 = idx & 15;
  int row = (idx >> 4) & 1023;
  int bb = (idx >> 14) & 3;
  int hp = idx >> 16;
  float mv[4], lv[4];
  float ms = -1e30f;
#pragma unroll
  for (int s = 0; s < 4; ++s) {
    size_t base = (((size_t)(hp * 4 + s) * 4 + bb) * 1024 + row) * 2;
    mv[s] = Part_ml[base];
    lv[s] = Part_ml[base + 1];
    ms = fmaxf(ms, mv[s]);
  }
  float denom = 0.0f, e[4];
#pragma unroll
  for (int s = 0; s < 4; ++s) { e[s] = __expf(mv[s] - ms); denom += lv[s] * e[s]; }
  float wgt = (hp < 2) ? mix_w[hp * 2] : 1.0f;
  float inv = wgt / denom;
  float out[4] = {0.f, 0.f, 0.f, 0.f};
#pragma unroll
  for (int s = 0; s < 4; ++s) {
    us4 ov = *(const us4*)&Part_o[(((size_t)(hp * 4 + s) * 4 + bb) * 1024 + row) * 64 + q4 * 4];
#pragma unroll
    for (int j = 0; j < 4; ++j) out[j] += e[s] * bf2f(ov[j]);
  }
  us4 pk = { f2bf(out[0] * inv), f2bf(out[1] * inv), f2bf(out[2] * inv), f2bf(out[3] * inv) };
  *(us4*)&Y[((size_t)bb * 1024 + row) * 640 + (hp + 2) * 64 + q4 * 4] = pk;
}

extern "C" void kernel_launch(void* const* d_in, const int* in_sizes, int n_in,
                              void* d_out, int out_size, void* d_ws, size_t ws_size,
                              hipStream_t stream) {
  const float* x     = (const float*)d_in[0];
  const float* Wq    = (const float*)d_in[2];
  const float* bq    = (const float*)d_in[3];
  const float* Wk    = (const float*)d_in[4];
  const float* bk    = (const float*)d_in[5];
  const float* Wv    = (const float*)d_in[6];
  const float* bv    = (const float*)d_in[7];
  const float* Wqml  = (const float*)d_in[8];
  const float* bqml  = (const float*)d_in[9];
  const float* Wkml  = (const float*)d_in[10];
  const float* bkml  = (const float*)d_in[11];
  const float* mixw  = (const float*)d_in[12];
  const float* Wp    = (const float*)d_in[13];
  const float* bp    = (const float*)d_in[14];
  const float* bclip = (const float*)d_in[15];
  const float* bclipml = (const float*)d_in[16];

  u16* xb   = (u16*)d_ws;                  // 4096*512
  u16* Wcat = xb + 4096 * 512;             // 1792*512
  u16* Wpx  = Wcat + 1792 * 512;           // 512*640
  u16* Ybuf = Wpx + 512 * 640;             // 4096*640
  u16* Vtb  = Ybuf + 4096 * 640;           // 4*512*1024
  u16* Pbuf = Vtb + 4 * 512 * 1024;        // 4096*1280
  float* bcat = (float*)(Pbuf + 4096 * 1280);  // 2048 f32
  u16* Part_o = (u16*)(bcat + 2048);       // 24*4*1024*64 bf16 = 12.6 MB
  float* Part_ml = (float*)(Part_o + 24 * 4 * 1024 * 64);  // 24*4*1024*2 f32

  prep_all<<<6919, 256, 0, stream>>>((const float4*)x, xb, Wq, Wk, Wv, Wqml, Wkml, Wp,
                                     bq, bk, bv, bqml, bkml, Wcat, Wpx, bcat);
  gemm_qkv<<<dim3(14, 32), 256, 0, stream>>>(xb, Wcat, bcat, Pbuf, Vtb);
  attn_k<<<dim3(8, 28, 4), 512, 0, stream>>>(Pbuf, Vtb, Ybuf, Part_o, Part_ml,
                                             mixw, bclip, bclipml);
  combine_k<<<1536, 256, 0, stream>>>(Part_o, Part_ml, Ybuf, mixw);
  gemm_out<<<dim3(8, 32), 256, 0, stream>>>(Ybuf, Wpx, bp, (float*)d_out);
}